// Round 6
// baseline (221.623 us; speedup 1.0000x reference)
//
#include <hip/hip_runtime.h>

// ColorHistogramLoss: B=32, C=3, H=W=512, BINS=64.
// loss = mean | hist(input)/N - hist(target)/N | over 96*64 bins.
//
// R6: hybrid DS-atomic + ballot, mixed INSIDE every wave (R5 put the two
// methods on different waves -> ballot concentrated on SIMDs 2-3 and ran
// serial at 79us while DS hid under it; 83us measured == ballot-bound).
// ds_add is fire-and-forget (no return), so each wave issues its 35 LDS
// atomics then does 29 ballot slots on VALU while the DS pipe drains.
// Measured costs: DS 0.91 cyc/pixel per CU (75us full), ballot 283 cyc per
// 64-pixel slot per SIMD (90us full). x=35/64 via DS -> max(41,41) ~ 45us.

#define BINS 64
#define PLANES 96          // B*C
#define PLANE_F4 65536     // 512*512/4
#define SEGS 32            // segments per plane
#define SEG_F4 2048        // PLANE_F4/SEGS
#define TPB 256
#define F4T 8              // float4 per thread per tensor (32 px)
#define DS_IN 17           // input pixels per thread via DS path
#define DS_TG 18           // target pixels per thread via DS path

// bin formula identical to R1-R5 (absmax 0): inputs in [-1,1) -> bin>=0
// guaranteed, only top clamp needed.
__device__ __forceinline__ int binof(float v) {
    float x = (v + 1.0f) * 31.5f;
    int bin = (int)x;
    return bin > 63 ? 63 : bin;
}

__global__ __launch_bounds__(TPB) void hist_diff_kernel(
        const float4* __restrict__ in4, const float4* __restrict__ tg4,
        int* __restrict__ gdiff) {
    __shared__ int lh[BINS];
    const int tid  = threadIdx.x;
    const int lane = tid & 63;
    if (tid < BINS) lh[tid] = 0;
    __syncthreads();

    const int plane = blockIdx.x >> 5;           // /SEGS
    const int seg   = blockIdx.x & (SEGS - 1);
    const long base = (long)plane * PLANE_F4 + (long)seg * SEG_F4 + tid;

    float4 a[F4T], b[F4T];
#pragma unroll
    for (int k = 0; k < F4T; ++k) a[k] = in4[base + k * TPB];
#pragma unroll
    for (int k = 0; k < F4T; ++k) b[k] = tg4[base + k * TPB];
    const float* av = (const float*)a;           // unrolled const indexing ->
    const float* bv = (const float*)b;           // stays in registers

    // ---- DS section first: fire-and-forget ds_add, pipe drains under ballot
#pragma unroll
    for (int p = 0; p < DS_IN; ++p) atomicAdd(&lh[binof(av[p])], 1);
#pragma unroll
    for (int p = 0; p < DS_TG; ++p) atomicAdd(&lh[binof(bv[p])], -1);

    // ---- ballot section: lane l of each wave counts bin l
    unsigned long long inv[6];
#pragma unroll
    for (int k = 0; k < 6; ++k)
        inv[k] = ((lane >> k) & 1) ? 0ull : ~0ull;

    int cin = 0, ctg = 0;
    auto slot = [&](float v, int& cnt) {
        int bin = binof(v);
        unsigned long long m =
            (__ballot(bin & 1)  ^ inv[0]) &
            (__ballot(bin & 2)  ^ inv[1]) &
            (__ballot(bin & 4)  ^ inv[2]) &
            (__ballot(bin & 8)  ^ inv[3]) &
            (__ballot(bin & 16) ^ inv[4]) &
            (__ballot(bin & 32) ^ inv[5]);
        cnt += __popcll(m);
    };
#pragma unroll
    for (int p = DS_IN; p < 32; ++p) slot(av[p], cin);
#pragma unroll
    for (int p = DS_TG; p < 32; ++p) slot(bv[p], ctg);

    const int bdiff = cin - ctg;
    if (bdiff != 0) atomicAdd(&lh[lane], bdiff); // merge ballot waves into lh

    __syncthreads();
    if (tid < BINS) {
        int v = lh[tid];
        if (v != 0) atomicAdd(&gdiff[plane * BINS + tid], v);
    }
}

__global__ __launch_bounds__(TPB) void reduce_abs_kernel(
        const int* __restrict__ gdiff, float* __restrict__ out) {
    int s = 0;
    for (int i = threadIdx.x; i < PLANES * BINS; i += TPB) {
        int v = gdiff[i];
        s += (v < 0) ? -v : v;
    }
#pragma unroll
    for (int off = 32; off > 0; off >>= 1) s += __shfl_down(s, off, 64);
    __shared__ int ws[TPB / 64];
    const int wid  = threadIdx.x >> 6;
    const int lane = threadIdx.x & 63;
    if (lane == 0) ws[wid] = s;
    __syncthreads();
    if (threadIdx.x == 0) {
        int total = 0;
#pragma unroll
        for (int w = 0; w < TPB / 64; ++w) total += ws[w];
        out[0] = (float)total * (1.0f / (262144.0f * 6144.0f));
    }
}

extern "C" void kernel_launch(void* const* d_in, const int* in_sizes, int n_in,
                              void* d_out, int out_size, void* d_ws, size_t ws_size,
                              hipStream_t stream) {
    const float4* inp = (const float4*)d_in[0];
    const float4* tgt = (const float4*)d_in[1];
    int* gdiff = (int*)d_ws;   // 96*64 signed counts, 24 KiB

    hipMemsetAsync(gdiff, 0, PLANES * BINS * sizeof(int), stream);
    hist_diff_kernel<<<PLANES * SEGS, TPB, 0, stream>>>(inp, tgt, gdiff);
    reduce_abs_kernel<<<1, TPB, 0, stream>>>(gdiff, (float*)d_out);
}